// Round 1
// baseline (254.658 us; speedup 1.0000x reference)
//
#include <hip/hip_runtime.h>

typedef float floatx4 __attribute__((ext_vector_type(4)));
typedef __bf16 bf16x8 __attribute__((ext_vector_type(8)));
typedef unsigned short u16x8 __attribute__((ext_vector_type(8)));
typedef unsigned short u16x4 __attribute__((ext_vector_type(4)));

#define GLDS16(g, l) __builtin_amdgcn_global_load_lds( \
    (__attribute__((address_space(1))) void*)(g), \
    (__attribute__((address_space(3))) void*)(l), 16, 0, 0)

__device__ __forceinline__ unsigned short f2bf(float f) {
    unsigned u = __float_as_uint(f);
    u += 0x7fffu + ((u >> 16) & 1u);   // RNE; inputs finite
    return (unsigned short)(u >> 16);
}

// ---------------- kernel 1: hidden fp32 -> bf16 ----------------
__global__ __launch_bounds__(256) void k_convert(const float* __restrict__ in,
                                                 unsigned short* __restrict__ out) {
    int idx = (blockIdx.x * 256 + threadIdx.x) * 8;
    const float4* p = (const float4*)(in + idx);
    float4 f0 = p[0], f1 = p[1];
    u16x8 o;
    o[0] = f2bf(f0.x); o[1] = f2bf(f0.y); o[2] = f2bf(f0.z); o[3] = f2bf(f0.w);
    o[4] = f2bf(f1.x); o[5] = f2bf(f1.y); o[6] = f2bf(f1.z); o[7] = f2bf(f1.w);
    *(u16x8*)(out + idx) = o;
}

// ---------------- kernel 2: W^T bf16: Wt[n][k] = [Wqk|Wv][k][n] ----------------
__global__ __launch_bounds__(256) void k_transpose(const float* __restrict__ Wqk,
                                                   const float* __restrict__ Wv,
                                                   unsigned short* __restrict__ Wt) {
    __shared__ unsigned short t[64][68];  // pad 68: phase-2 u16x4 reads 8B-aligned
    const int tid = threadIdx.x;
    const int n0 = blockIdx.x * 64;   // 48 tiles over n=3072
    const int k0 = blockIdx.y * 64;   // 16 tiles over k=1024
    const int nl = tid & 63;
    const int kb = tid >> 6;          // 0..3
    const int ng = n0 + nl;
#pragma unroll
    for (int i = 0; i < 16; ++i) {
        int kl = kb + i * 4;
        float v = (n0 < 2048) ? Wqk[(size_t)(k0 + kl) * 2048 + ng]
                              : Wv[(size_t)(k0 + kl) * 1024 + (ng - 2048)];
        t[nl][kl] = f2bf(v);
    }
    __syncthreads();
    const int k4 = (tid & 15) * 4;
    const int nb = tid >> 4;          // 0..15
#pragma unroll
    for (int i = 0; i < 4; ++i) {
        int n2 = nb + i * 16;
        u16x4 o;
        o[0] = t[n2][k4]; o[1] = t[n2][k4 + 1]; o[2] = t[n2][k4 + 2]; o[3] = t[n2][k4 + 3];
        *(u16x4*)(Wt + (size_t)(n0 + n2) * 1024 + k0 + k4) = o;
    }
}

// ---------------- kernel 3: QKV GEMM (m97 structure) ----------------
// C[m][n] = sum_k A[m][k] * Wt[n][k]; epilogue: +bias, Q*0.125, scatter to [BH][S][64]
__global__ __launch_bounds__(256, 2) void k_gemm_qkv(
    const unsigned short* __restrict__ A,    // [4096][1024] bf16
    const unsigned short* __restrict__ Bt,   // [3072][1024] bf16
    const float* __restrict__ bqk, const float* __restrict__ bvv,
    unsigned short* __restrict__ Qo, unsigned short* __restrict__ Ko,
    unsigned short* __restrict__ Vo) {
    __shared__ unsigned short As[128 * 32];  // unpadded: global_load_lds lane*16 layout
    __shared__ unsigned short Bs[128 * 32];
    const int tid = threadIdx.x;
    const int lane = tid & 63;
    const int w = tid >> 6;
    const int m0 = blockIdx.x * 128;  // 32
    const int n0 = blockIdx.y * 128;  // 24
    const int wm = (w & 1) * 64;
    const int wn = (w >> 1) * 64;
    const int rC = lane >> 2;         // row within 16-row chunk
    const int kC = (lane & 3) * 8;    // k element offset
    const int c0 = w * 2;             // this wave's first chunk (2 chunks/wave)

    floatx4 acc[4][4] = {};

    const unsigned short* agp0 = A + (size_t)(m0 + c0 * 16 + rC) * 1024 + kC;
    const unsigned short* agp1 = agp0 + 16 * 1024;
    const unsigned short* bgp0 = Bt + (size_t)(n0 + c0 * 16 + rC) * 1024 + kC;
    const unsigned short* bgp1 = bgp0 + 16 * 1024;
    unsigned short* al = As + c0 * 512;
    unsigned short* bl = Bs + c0 * 512;

    for (int k0 = 0; k0 < 1024; k0 += 32) {
        GLDS16(agp0 + k0, al);
        GLDS16(agp1 + k0, al + 512);
        GLDS16(bgp0 + k0, bl);
        GLDS16(bgp1 + k0, bl + 512);
        __syncthreads();
        const unsigned short* ap = As + (wm + (lane & 15)) * 32 + (lane >> 4) * 8;
        const unsigned short* bp = Bs + (wn + (lane & 15)) * 32 + (lane >> 4) * 8;
        bf16x8 af[4], bfr[4];
#pragma unroll
        for (int mi = 0; mi < 4; ++mi) af[mi] = *(const bf16x8*)(ap + mi * 16 * 32);
#pragma unroll
        for (int ni = 0; ni < 4; ++ni) bfr[ni] = *(const bf16x8*)(bp + ni * 16 * 32);
#pragma unroll
        for (int mi = 0; mi < 4; ++mi)
#pragma unroll
            for (int ni = 0; ni < 4; ++ni)
                acc[mi][ni] = __builtin_amdgcn_mfma_f32_16x16x32_bf16(af[mi], bfr[ni],
                                                                      acc[mi][ni], 0, 0, 0);
        __syncthreads();
    }
    // epilogue: C layout col=lane&15, row=(lane>>4)*4+r
#pragma unroll
    for (int ni = 0; ni < 4; ++ni) {
        const int n = n0 + wn + ni * 16 + (lane & 15);
        float bias; unsigned short* dst; int hd; float scale = 1.0f;
        if (n < 1024)      { bias = bqk[n];        dst = Qo; hd = n;        scale = 0.125f; }
        else if (n < 2048) { bias = bqk[n];        dst = Ko; hd = n - 1024; }
        else               { bias = bvv[n - 2048]; dst = Vo; hd = n - 2048; }
        const int h = hd >> 6, d = hd & 63;
#pragma unroll
        for (int mi = 0; mi < 4; ++mi) {
#pragma unroll
            for (int r = 0; r < 4; ++r) {
                const int m = m0 + wm + mi * 16 + ((lane >> 4) << 2) + r;
                const int b = m >> 11, s = m & 2047;
                float v = (acc[mi][ni][r] + bias) * scale;
                dst[((size_t)(b * 16 + h) * 2048 + s) * 64 + d] = f2bf(v);
            }
        }
    }
}

// ---------------- kernel 4: causal flash attention ----------------
// grid: 1024 blocks = BH(32) x qtiles(32); block 256 thr; wave w owns 16 q-rows
__global__ __launch_bounds__(256, 2) void k_attn(
    const unsigned short* __restrict__ Q, const unsigned short* __restrict__ K,
    const unsigned short* __restrict__ V, float* __restrict__ out) {
    __shared__ unsigned short Ks[64 * 72];      // [kv][d] pad->72
    __shared__ unsigned short Vt[64 * 72];      // [d][kv] pad->72 (transposed)
    __shared__ unsigned short Ps[4][16 * 72];   // per-wave P tile [q][kv]
    const int tid = threadIdx.x;
    const int lane = tid & 63;
    const int w = tid >> 6;
    const int bh = blockIdx.x >> 5;
    const int qt = 31 - (blockIdx.x & 31);      // heavy tiles first
    const int q0 = qt * 64;
    const int qw = q0 + w * 16;
    const size_t base = (size_t)bh * (2048 * 64);

    bf16x8 aQ[2];  // A-frag: m=lane&15, k=quad*8+j (Q pre-scaled by 0.125 in GEMM)
    {
        const unsigned short* qp = Q + base + (size_t)(qw + (lane & 15)) * 64 + ((lane >> 4) * 8);
        aQ[0] = *(const bf16x8*)qp;
        aQ[1] = *(const bf16x8*)(qp + 32);
    }
    floatx4 o[4] = {};  // O: q=quad*4+r, d=dt*16+(lane&15)
    float mrow[4] = {-3e38f, -3e38f, -3e38f, -3e38f};
    float lrow[4] = {0.f, 0.f, 0.f, 0.f};

    const int srow = w * 16 + (lane >> 2);  // staging row
    const int sd0 = (lane & 3) * 16;

    const int nkv = qt + 1;
    for (int t = 0; t < nkv; ++t) {
        const int kv0 = t * 64;
        __syncthreads();
        {   // stage K [kv][d] (vector), V transposed -> Vt[d][kv] (scalar)
            const unsigned short* kp = K + base + (size_t)(kv0 + srow) * 64 + sd0;
            u16x8 ka = *(const u16x8*)kp;
            u16x8 kb = *(const u16x8*)(kp + 8);
            *(u16x8*)&Ks[srow * 72 + sd0] = ka;
            *(u16x8*)&Ks[srow * 72 + sd0 + 8] = kb;
            const unsigned short* vp = V + base + (size_t)(kv0 + srow) * 64 + sd0;
            u16x8 va = *(const u16x8*)vp;
            u16x8 vb = *(const u16x8*)(vp + 8);
#pragma unroll
            for (int j = 0; j < 8; ++j) Vt[(sd0 + j) * 72 + srow] = va[j];
#pragma unroll
            for (int j = 0; j < 8; ++j) Vt[(sd0 + 8 + j) * 72 + srow] = vb[j];
        }
        __syncthreads();

        // S = Q K^T  (scores in C layout: q=quad*4+r, kv=nt*16+(lane&15))
        floatx4 st[4] = {};
#pragma unroll
        for (int nt = 0; nt < 4; ++nt)
#pragma unroll
            for (int kk = 0; kk < 2; ++kk) {
                bf16x8 bk = *(const bf16x8*)&Ks[(nt * 16 + (lane & 15)) * 72 + kk * 32 + (lane >> 4) * 8];
                st[nt] = __builtin_amdgcn_mfma_f32_16x16x32_bf16(aQ[kk], bk, st[nt], 0, 0, 0);
            }

        // causal mask + online softmax
        const int kvb = kv0 + (lane & 15);
        const int qg0 = qw + ((lane >> 4) << 2);
        float mcur[4] = {-3e38f, -3e38f, -3e38f, -3e38f};
#pragma unroll
        for (int nt = 0; nt < 4; ++nt)
#pragma unroll
            for (int r = 0; r < 4; ++r) {
                float sv = st[nt][r];
                if (kvb + nt * 16 > qg0 + r) sv = -3e38f;
                st[nt][r] = sv;
                mcur[r] = fmaxf(mcur[r], sv);
            }
#pragma unroll
        for (int off = 1; off < 16; off <<= 1)
#pragma unroll
            for (int r = 0; r < 4; ++r) mcur[r] = fmaxf(mcur[r], __shfl_xor(mcur[r], off, 64));
        float alpha[4], lsum[4];
#pragma unroll
        for (int r = 0; r < 4; ++r) {
            float mnew = fmaxf(mrow[r], mcur[r]);
            alpha[r] = __expf(mrow[r] - mnew);
            mrow[r] = mnew;
            lsum[r] = 0.f;
        }
#pragma unroll
        for (int nt = 0; nt < 4; ++nt)
#pragma unroll
            for (int r = 0; r < 4; ++r) {
                float p = __expf(st[nt][r] - mrow[r]);
                st[nt][r] = p;
                lsum[r] += p;
            }
        // P: C layout -> LDS -> A layout (m120-verified round trip)
        unsigned short* pw = &Ps[w][0];
#pragma unroll
        for (int nt = 0; nt < 4; ++nt)
#pragma unroll
            for (int r = 0; r < 4; ++r)
                pw[(((lane >> 4) << 2) + r) * 72 + nt * 16 + (lane & 15)] = f2bf(st[nt][r]);
#pragma unroll
        for (int off = 1; off < 16; off <<= 1)
#pragma unroll
            for (int r = 0; r < 4; ++r) lsum[r] += __shfl_xor(lsum[r], off, 64);
#pragma unroll
        for (int r = 0; r < 4; ++r) lrow[r] = lrow[r] * alpha[r] + lsum[r];
#pragma unroll
        for (int dt = 0; dt < 4; ++dt)
#pragma unroll
            for (int r = 0; r < 4; ++r) o[dt][r] *= alpha[r];
        // O += P V
#pragma unroll
        for (int kk = 0; kk < 2; ++kk) {
            bf16x8 apf = *(const bf16x8*)&pw[(lane & 15) * 72 + kk * 32 + (lane >> 4) * 8];
#pragma unroll
            for (int dt = 0; dt < 4; ++dt) {
                bf16x8 bvf = *(const bf16x8*)&Vt[(dt * 16 + (lane & 15)) * 72 + kk * 32 + (lane >> 4) * 8];
                o[dt] = __builtin_amdgcn_mfma_f32_16x16x32_bf16(apf, bvf, o[dt], 0, 0, 0);
            }
        }
    }
    // epilogue: out[b][s][h*64+d] fp32
    const int b = bh >> 4, h = bh & 15;
#pragma unroll
    for (int r = 0; r < 4; ++r) {
        const int qg = qw + ((lane >> 4) << 2) + r;
        const float inv = 1.0f / lrow[r];
        float* op = out + (size_t)(b * 2048 + qg) * 1024 + h * 64 + (lane & 15);
#pragma unroll
        for (int dt = 0; dt < 4; ++dt) op[dt * 16] = o[dt][r] * inv;
    }
}

extern "C" void kernel_launch(void* const* d_in, const int* in_sizes, int n_in,
                              void* d_out, int out_size, void* d_ws, size_t ws_size,
                              hipStream_t stream) {
    const float* hidden = (const float*)d_in[0];   // [2,2048,1024]
    const float* Wqk    = (const float*)d_in[1];   // [1024,2048]
    const float* bqk    = (const float*)d_in[2];   // [2048]
    const float* Wv     = (const float*)d_in[3];   // [1024,1024]
    const float* bvv    = (const float*)d_in[4];   // [1024]
    float* out = (float*)d_out;                    // [2,2048,1024]

    unsigned short* Abf = (unsigned short*)d_ws;        // 4096*1024
    unsigned short* Wt  = Abf + 4096 * 1024;            // 3072*1024
    unsigned short* Qo  = Wt + 3072 * 1024;             // 32*2048*64 each
    unsigned short* Ko  = Qo + 32 * 2048 * 64;
    unsigned short* Vo  = Ko + 32 * 2048 * 64;

    k_convert<<<2048, 256, 0, stream>>>(hidden, Abf);
    k_transpose<<<dim3(48, 16), 256, 0, stream>>>(Wqk, Wv, Wt);
    k_gemm_qkv<<<dim3(32, 24), 256, 0, stream>>>(Abf, Wt, bqk, bvv, Qo, Ko, Vo);
    k_attn<<<1024, 256, 0, stream>>>(Qo, Ko, Vo, out);
}

// Round 2
// 184.312 us; speedup vs baseline: 1.3817x; 1.3817x over previous
//
#include <hip/hip_runtime.h>

typedef float floatx4 __attribute__((ext_vector_type(4)));
typedef __bf16 bf16x8 __attribute__((ext_vector_type(8)));
typedef unsigned short u16x8 __attribute__((ext_vector_type(8)));
typedef unsigned short u16x4 __attribute__((ext_vector_type(4)));

#define GLDS16(g, l) __builtin_amdgcn_global_load_lds( \
    (__attribute__((address_space(1))) void*)(g), \
    (__attribute__((address_space(3))) void*)(l), 16, 0, 0)

__device__ __forceinline__ unsigned short f2bf(float f) {
    unsigned u = __float_as_uint(f);
    u += 0x7fffu + ((u >> 16) & 1u);   // RNE; inputs finite
    return (unsigned short)(u >> 16);
}

// ---------------- kernel 1: hidden fp32 -> bf16 ----------------
__global__ __launch_bounds__(256) void k_convert(const float* __restrict__ in,
                                                 unsigned short* __restrict__ out) {
    int idx = (blockIdx.x * 256 + threadIdx.x) * 8;
    const float4* p = (const float4*)(in + idx);
    float4 f0 = p[0], f1 = p[1];
    u16x8 o;
    o[0] = f2bf(f0.x); o[1] = f2bf(f0.y); o[2] = f2bf(f0.z); o[3] = f2bf(f0.w);
    o[4] = f2bf(f1.x); o[5] = f2bf(f1.y); o[6] = f2bf(f1.z); o[7] = f2bf(f1.w);
    *(u16x8*)(out + idx) = o;
}

// ---------------- kernel 2: W^T bf16: Wt[n][k] = [Wqk|Wv][k][n] ----------------
__global__ __launch_bounds__(256) void k_transpose(const float* __restrict__ Wqk,
                                                   const float* __restrict__ Wv,
                                                   unsigned short* __restrict__ Wt) {
    __shared__ unsigned short t[64][68];
    const int tid = threadIdx.x;
    const int n0 = blockIdx.x * 64;   // 48 tiles over n=3072
    const int k0 = blockIdx.y * 64;   // 16 tiles over k=1024
    const int nl = tid & 63;
    const int kb = tid >> 6;          // 0..3
    const int ng = n0 + nl;
#pragma unroll
    for (int i = 0; i < 16; ++i) {
        int kl = kb + i * 4;
        float v = (n0 < 2048) ? Wqk[(size_t)(k0 + kl) * 2048 + ng]
                              : Wv[(size_t)(k0 + kl) * 1024 + (ng - 2048)];
        t[nl][kl] = f2bf(v);
    }
    __syncthreads();
    const int k4 = (tid & 15) * 4;
    const int nb = tid >> 4;          // 0..15
#pragma unroll
    for (int i = 0; i < 4; ++i) {
        int n2 = nb + i * 16;
        u16x4 o;
        o[0] = t[n2][k4]; o[1] = t[n2][k4 + 1]; o[2] = t[n2][k4 + 2]; o[3] = t[n2][k4 + 3];
        *(u16x4*)(Wt + (size_t)(n0 + n2) * 1024 + k0 + k4) = o;
    }
}

// ---------------- kernel 3: QKV GEMM (m97 structure) ----------------
// C[m][n] = sum_k A[m][k]*Wt[n][k]; epilogue: +bias, Q*0.125, scatter:
//   Q,K -> [bh][s][64] ; V -> transposed [bh][d=64][s=2048]
__global__ __launch_bounds__(256, 2) void k_gemm_qkv(
    const unsigned short* __restrict__ A,    // [4096][1024] bf16
    const unsigned short* __restrict__ Bt,   // [3072][1024] bf16
    const float* __restrict__ bqk, const float* __restrict__ bvv,
    unsigned short* __restrict__ Qo, unsigned short* __restrict__ Ko,
    unsigned short* __restrict__ VoT) {
    __shared__ unsigned short As[128 * 32];  // unpadded: global_load_lds layout
    __shared__ unsigned short Bs[128 * 32];
    const int tid = threadIdx.x;
    const int lane = tid & 63;
    const int w = tid >> 6;
    const int l15 = lane & 15;
    const int quad = lane >> 4;
    const int m0 = blockIdx.x * 128;  // 32
    const int n0 = blockIdx.y * 128;  // 24
    const int wm = (w & 1) * 64;
    const int wn = (w >> 1) * 64;
    const int rC = lane >> 2;
    const int kC = (lane & 3) * 8;
    const int c0 = w * 2;

    floatx4 acc[4][4] = {};

    const unsigned short* agp0 = A + (size_t)(m0 + c0 * 16 + rC) * 1024 + kC;
    const unsigned short* agp1 = agp0 + 16 * 1024;
    const unsigned short* bgp0 = Bt + (size_t)(n0 + c0 * 16 + rC) * 1024 + kC;
    const unsigned short* bgp1 = bgp0 + 16 * 1024;
    unsigned short* al = As + c0 * 512;
    unsigned short* bl = Bs + c0 * 512;

    for (int k0 = 0; k0 < 1024; k0 += 32) {
        GLDS16(agp0 + k0, al);
        GLDS16(agp1 + k0, al + 512);
        GLDS16(bgp0 + k0, bl);
        GLDS16(bgp1 + k0, bl + 512);
        __syncthreads();
        const unsigned short* ap = As + (wm + l15) * 32 + quad * 8;
        const unsigned short* bp = Bs + (wn + l15) * 32 + quad * 8;
        bf16x8 af[4], bfr[4];
#pragma unroll
        for (int mi = 0; mi < 4; ++mi) af[mi] = *(const bf16x8*)(ap + mi * 16 * 32);
#pragma unroll
        for (int ni = 0; ni < 4; ++ni) bfr[ni] = *(const bf16x8*)(bp + ni * 16 * 32);
#pragma unroll
        for (int mi = 0; mi < 4; ++mi)
#pragma unroll
            for (int ni = 0; ni < 4; ++ni)
                acc[mi][ni] = __builtin_amdgcn_mfma_f32_16x16x32_bf16(af[mi], bfr[ni],
                                                                      acc[mi][ni], 0, 0, 0);
        __syncthreads();
    }
    // epilogue: C layout col=l15, row=quad*4+r
#pragma unroll
    for (int ni = 0; ni < 4; ++ni) {
        const int n = n0 + wn + ni * 16 + l15;
        if (n < 2048) {   // Q or K: [bh][s][64]
            const float bias = bqk[n];
            const bool isQ = n < 1024;
            unsigned short* dst = isQ ? Qo : Ko;
            const int hd = isQ ? n : n - 1024;
            const float scale = isQ ? 0.125f : 1.0f;
            const int h = hd >> 6, d = hd & 63;
#pragma unroll
            for (int mi = 0; mi < 4; ++mi)
#pragma unroll
                for (int r = 0; r < 4; ++r) {
                    const int m = m0 + wm + mi * 16 + (quad << 2) + r;
                    const int b = m >> 11, s = m & 2047;
                    dst[((size_t)(b * 16 + h) * 2048 + s) * 64 + d] =
                        f2bf((acc[mi][ni][r] + bias) * scale);
                }
        } else {          // V transposed: [bh][d][s], 4 consecutive s per lane
            const float bias = bvv[n - 2048];
            const int hd = n - 2048;
            const int h = hd >> 6, d = hd & 63;
#pragma unroll
            for (int mi = 0; mi < 4; ++mi) {
                const int m = m0 + wm + mi * 16 + (quad << 2);
                const int b = m >> 11, s = m & 2047;
                u16x4 o4;
#pragma unroll
                for (int r = 0; r < 4; ++r) o4[r] = f2bf(acc[mi][ni][r] + bias);
                *(u16x4*)(VoT + ((size_t)(b * 16 + h) * 64 + d) * 2048 + s) = o4;
            }
        }
    }
}

// ---------------- kernel 4: causal flash attention ----------------
// grid: 512 = bh(32) x pair(16); block 256 thr / 4 waves; wave owns 16 q-rows.
// Each block runs q-tile p then q-tile 31-p: exactly 33 kv-steps -> perfect balance.
__global__ __launch_bounds__(256, 2) void k_attn(
    const unsigned short* __restrict__ Q, const unsigned short* __restrict__ K,
    const unsigned short* __restrict__ Vt, float* __restrict__ out) {
    __shared__ unsigned short Ks[64 * 72];      // [kv][d] pad->72
    __shared__ unsigned short Vs[64 * 72];      // [d][kv] pad->72
    __shared__ unsigned short Ps[4][16 * 72];   // per-wave P tile [q][kv]
    const int tid = threadIdx.x;
    const int lane = tid & 63;
    const int w = tid >> 6;
    const int l15 = lane & 15;
    const int quad = lane >> 4;
    const int bh = blockIdx.x >> 4;
    const int p = blockIdx.x & 15;
    const size_t base = (size_t)bh * (2048 * 64);

    // staging: thread covers rows {w*16+r8, w*16+8+r8}, 8 cols of u16x8
    const int r8 = lane >> 3;
    const int c8 = (lane & 7) * 8;
    unsigned short* kls0 = &Ks[(w * 16 + r8) * 72 + c8];
    unsigned short* kls1 = &Ks[(w * 16 + 8 + r8) * 72 + c8];
    unsigned short* vls0 = &Vs[(w * 16 + r8) * 72 + c8];
    unsigned short* vls1 = &Vs[(w * 16 + 8 + r8) * 72 + c8];
    const unsigned short* kg = K + base + (size_t)(w * 16 + r8) * 64 + c8;
    const unsigned short* vg = Vt + base + (size_t)(w * 16 + r8) * 2048 + c8;

    const int b = bh >> 4, h = bh & 15;

    for (int pass = 0; pass < 2; ++pass) {
        const int qt = pass ? (31 - p) : p;
        const int qw = qt * 64 + w * 16;

        bf16x8 aQ[2];   // A-frag: m=l15, k=quad*8+j (Q pre-scaled by 0.125)
        {
            const unsigned short* qp = Q + base + (size_t)(qw + l15) * 64 + quad * 8;
            aQ[0] = *(const bf16x8*)qp;
            aQ[1] = *(const bf16x8*)(qp + 32);
        }
        floatx4 o[4] = {};
        float mrow[4] = {-3e38f, -3e38f, -3e38f, -3e38f};
        float lrow[4] = {0.f, 0.f, 0.f, 0.f};

        // prefetch kv tile 0
        u16x8 kr0 = *(const u16x8*)(kg);
        u16x8 kr1 = *(const u16x8*)(kg + 512);
        u16x8 vr0 = *(const u16x8*)(vg);
        u16x8 vr1 = *(const u16x8*)(vg + 8 * 2048);

        for (int t = 0; t <= qt; ++t) {
            __syncthreads();                       // prior step's LDS reads done
            *(u16x8*)kls0 = kr0; *(u16x8*)kls1 = kr1;
            *(u16x8*)vls0 = vr0; *(u16x8*)vls1 = vr1;
            __syncthreads();                       // tile staged
            if (t < qt) {                          // prefetch next (overlaps compute)
                const int kv1 = (t + 1) * 64;
                kr0 = *(const u16x8*)(kg + (size_t)kv1 * 64);
                kr1 = *(const u16x8*)(kg + (size_t)kv1 * 64 + 512);
                vr0 = *(const u16x8*)(vg + kv1);
                vr1 = *(const u16x8*)(vg + kv1 + 8 * 2048);
            }

            // S = Q K^T  (C layout: q=quad*4+r, kv=nt*16+l15)
            floatx4 st[4] = {};
#pragma unroll
            for (int kk = 0; kk < 2; ++kk)
#pragma unroll
                for (int nt = 0; nt < 4; ++nt) {
                    bf16x8 bk = *(const bf16x8*)&Ks[(nt * 16 + l15) * 72 + kk * 32 + quad * 8];
                    st[nt] = __builtin_amdgcn_mfma_f32_16x16x32_bf16(aQ[kk], bk, st[nt], 0, 0, 0);
                }

            if (t == qt) {   // diagonal tile only: causal mask
                const int kvb = t * 64 + l15;
                const int qg0 = qw + (quad << 2);
#pragma unroll
                for (int nt = 0; nt < 4; ++nt)
#pragma unroll
                    for (int r = 0; r < 4; ++r)
                        if (kvb + nt * 16 > qg0 + r) st[nt][r] = -3e38f;
            }

            float mcur[4] = {-3e38f, -3e38f, -3e38f, -3e38f};
#pragma unroll
            for (int nt = 0; nt < 4; ++nt)
#pragma unroll
                for (int r = 0; r < 4; ++r) mcur[r] = fmaxf(mcur[r], st[nt][r]);
#pragma unroll
            for (int off = 1; off < 16; off <<= 1)
#pragma unroll
                for (int r = 0; r < 4; ++r) mcur[r] = fmaxf(mcur[r], __shfl_xor(mcur[r], off, 64));
            float alpha[4], lsum[4];
#pragma unroll
            for (int r = 0; r < 4; ++r) {
                float mnew = fmaxf(mrow[r], mcur[r]);
                alpha[r] = __expf(mrow[r] - mnew);
                mrow[r] = mnew;
                lsum[r] = 0.f;
            }
#pragma unroll
            for (int nt = 0; nt < 4; ++nt)
#pragma unroll
                for (int r = 0; r < 4; ++r) {
                    float pv = __expf(st[nt][r] - mrow[r]);
                    st[nt][r] = pv;
                    lsum[r] += pv;
                }
            // P: C layout -> LDS -> A layout (per-wave buffer: no barrier needed)
            unsigned short* pw = &Ps[w][0];
#pragma unroll
            for (int nt = 0; nt < 4; ++nt)
#pragma unroll
                for (int r = 0; r < 4; ++r)
                    pw[((quad << 2) + r) * 72 + nt * 16 + l15] = f2bf(st[nt][r]);
#pragma unroll
            for (int off = 1; off < 16; off <<= 1)
#pragma unroll
                for (int r = 0; r < 4; ++r) lsum[r] += __shfl_xor(lsum[r], off, 64);
#pragma unroll
            for (int r = 0; r < 4; ++r) lrow[r] = lrow[r] * alpha[r] + lsum[r];
#pragma unroll
            for (int dt = 0; dt < 4; ++dt)
#pragma unroll
                for (int r = 0; r < 4; ++r) o[dt][r] *= alpha[r];
            // O += P V
#pragma unroll
            for (int kk = 0; kk < 2; ++kk) {
                bf16x8 apf = *(const bf16x8*)&pw[l15 * 72 + kk * 32 + quad * 8];
#pragma unroll
                for (int dt = 0; dt < 4; ++dt) {
                    bf16x8 bvf = *(const bf16x8*)&Vs[(dt * 16 + l15) * 72 + kk * 32 + quad * 8];
                    o[dt] = __builtin_amdgcn_mfma_f32_16x16x32_bf16(apf, bvf, o[dt], 0, 0, 0);
                }
            }
        }
        // epilogue: out[b][s][h*64+d] fp32
#pragma unroll
        for (int r = 0; r < 4; ++r) {
            const int qg = qw + (quad << 2) + r;
            const float inv = 1.0f / lrow[r];
            float* op = out + (size_t)(b * 2048 + qg) * 1024 + h * 64 + l15;
#pragma unroll
            for (int dt = 0; dt < 4; ++dt) op[dt * 16] = o[dt][r] * inv;
        }
    }
}

extern "C" void kernel_launch(void* const* d_in, const int* in_sizes, int n_in,
                              void* d_out, int out_size, void* d_ws, size_t ws_size,
                              hipStream_t stream) {
    const float* hidden = (const float*)d_in[0];   // [2,2048,1024]
    const float* Wqk    = (const float*)d_in[1];   // [1024,2048]
    const float* bqk    = (const float*)d_in[2];   // [2048]
    const float* Wv     = (const float*)d_in[3];   // [1024,1024]
    const float* bvv    = (const float*)d_in[4];   // [1024]
    float* out = (float*)d_out;                    // [2,2048,1024]

    unsigned short* Abf = (unsigned short*)d_ws;        // 4096*1024
    unsigned short* Wt  = Abf + 4096 * 1024;            // 3072*1024
    unsigned short* Qo  = Wt + 3072 * 1024;             // 32*2048*64 each
    unsigned short* Ko  = Qo + 32 * 2048 * 64;
    unsigned short* VoT = Ko + 32 * 2048 * 64;          // [bh][64][2048]

    k_convert<<<2048, 256, 0, stream>>>(hidden, Abf);
    k_transpose<<<dim3(48, 16), 256, 0, stream>>>(Wqk, Wv, Wt);
    k_gemm_qkv<<<dim3(32, 24), 256, 0, stream>>>(Abf, Wt, bqk, bvv, Qo, Ko, VoT);
    k_attn<<<512, 256, 0, stream>>>(Qo, Ko, VoT, out);
}

// Round 3
// 177.623 us; speedup vs baseline: 1.4337x; 1.0377x over previous
//
#include <hip/hip_runtime.h>

typedef float floatx4 __attribute__((ext_vector_type(4)));
typedef float floatx16 __attribute__((ext_vector_type(16)));
typedef __bf16 bf16x8 __attribute__((ext_vector_type(8)));
typedef unsigned short u16x8 __attribute__((ext_vector_type(8)));
typedef unsigned short u16x4 __attribute__((ext_vector_type(4)));

#define GLDS16(g, l) __builtin_amdgcn_global_load_lds( \
    (__attribute__((address_space(1))) void*)(g), \
    (__attribute__((address_space(3))) void*)(l), 16, 0, 0)

__device__ __forceinline__ unsigned short f2bf(float f) {
    unsigned u = __float_as_uint(f);
    u += 0x7fffu + ((u >> 16) & 1u);   // RNE; inputs finite
    return (unsigned short)(u >> 16);
}

#if __has_builtin(__builtin_amdgcn_cvt_pk_bf16_f32)
__device__ __forceinline__ unsigned pk2(float a, float b) {
    typedef __bf16 bf16x2 __attribute__((ext_vector_type(2)));
    union { bf16x2 v; unsigned u; } cv;
    cv.v = __builtin_amdgcn_cvt_pk_bf16_f32(a, b);
    return cv.u;
}
#else
__device__ __forceinline__ unsigned pk2(float a, float b) {
    return (unsigned)f2bf(a) | ((unsigned)f2bf(b) << 16);
}
#endif

// ---------------- kernel 1: hidden fp32 -> bf16 ----------------
__global__ __launch_bounds__(256) void k_convert(const float* __restrict__ in,
                                                 unsigned short* __restrict__ out) {
    int idx = (blockIdx.x * 256 + threadIdx.x) * 8;
    const float4* p = (const float4*)(in + idx);
    float4 f0 = p[0], f1 = p[1];
    u16x8 o;
    o[0] = f2bf(f0.x); o[1] = f2bf(f0.y); o[2] = f2bf(f0.z); o[3] = f2bf(f0.w);
    o[4] = f2bf(f1.x); o[5] = f2bf(f1.y); o[6] = f2bf(f1.z); o[7] = f2bf(f1.w);
    *(u16x8*)(out + idx) = o;
}

// ---------------- kernel 2: W^T bf16: Wt[n][k] = [Wqk|Wv][k][n] ----------------
__global__ __launch_bounds__(256) void k_transpose(const float* __restrict__ Wqk,
                                                   const float* __restrict__ Wv,
                                                   unsigned short* __restrict__ Wt) {
    __shared__ unsigned short t[64][68];
    const int tid = threadIdx.x;
    const int n0 = blockIdx.x * 64;
    const int k0 = blockIdx.y * 64;
    const int nl = tid & 63;
    const int kb = tid >> 6;
    const int ng = n0 + nl;
#pragma unroll
    for (int i = 0; i < 16; ++i) {
        int kl = kb + i * 4;
        float v = (n0 < 2048) ? Wqk[(size_t)(k0 + kl) * 2048 + ng]
                              : Wv[(size_t)(k0 + kl) * 1024 + (ng - 2048)];
        t[nl][kl] = f2bf(v);
    }
    __syncthreads();
    const int k4 = (tid & 15) * 4;
    const int nb = tid >> 4;
#pragma unroll
    for (int i = 0; i < 4; ++i) {
        int n2 = nb + i * 16;
        u16x4 o;
        o[0] = t[n2][k4]; o[1] = t[n2][k4 + 1]; o[2] = t[n2][k4 + 2]; o[3] = t[n2][k4 + 3];
        *(u16x4*)(Wt + (size_t)(n0 + n2) * 1024 + k0 + k4) = o;
    }
}

// ---------------- kernel 3: QKV GEMM (m97 structure) ----------------
__global__ __launch_bounds__(256, 2) void k_gemm_qkv(
    const unsigned short* __restrict__ A,
    const unsigned short* __restrict__ Bt,
    const float* __restrict__ bqk, const float* __restrict__ bvv,
    unsigned short* __restrict__ Qo, unsigned short* __restrict__ Ko,
    unsigned short* __restrict__ VoT) {
    __shared__ unsigned short As[128 * 32];
    __shared__ unsigned short Bs[128 * 32];
    const int tid = threadIdx.x;
    const int lane = tid & 63;
    const int w = tid >> 6;
    const int l15 = lane & 15;
    const int quad = lane >> 4;
    const int m0 = blockIdx.x * 128;
    const int n0 = blockIdx.y * 128;
    const int wm = (w & 1) * 64;
    const int wn = (w >> 1) * 64;
    const int rC = lane >> 2;
    const int kC = (lane & 3) * 8;
    const int c0 = w * 2;

    floatx4 acc[4][4] = {};

    const unsigned short* agp0 = A + (size_t)(m0 + c0 * 16 + rC) * 1024 + kC;
    const unsigned short* agp1 = agp0 + 16 * 1024;
    const unsigned short* bgp0 = Bt + (size_t)(n0 + c0 * 16 + rC) * 1024 + kC;
    const unsigned short* bgp1 = bgp0 + 16 * 1024;
    unsigned short* al = As + c0 * 512;
    unsigned short* bl = Bs + c0 * 512;

    for (int k0 = 0; k0 < 1024; k0 += 32) {
        GLDS16(agp0 + k0, al);
        GLDS16(agp1 + k0, al + 512);
        GLDS16(bgp0 + k0, bl);
        GLDS16(bgp1 + k0, bl + 512);
        __syncthreads();
        const unsigned short* ap = As + (wm + l15) * 32 + quad * 8;
        const unsigned short* bp = Bs + (wn + l15) * 32 + quad * 8;
        bf16x8 af[4], bfr[4];
#pragma unroll
        for (int mi = 0; mi < 4; ++mi) af[mi] = *(const bf16x8*)(ap + mi * 16 * 32);
#pragma unroll
        for (int ni = 0; ni < 4; ++ni) bfr[ni] = *(const bf16x8*)(bp + ni * 16 * 32);
#pragma unroll
        for (int mi = 0; mi < 4; ++mi)
#pragma unroll
            for (int ni = 0; ni < 4; ++ni)
                acc[mi][ni] = __builtin_amdgcn_mfma_f32_16x16x32_bf16(af[mi], bfr[ni],
                                                                      acc[mi][ni], 0, 0, 0);
        __syncthreads();
    }
#pragma unroll
    for (int ni = 0; ni < 4; ++ni) {
        const int n = n0 + wn + ni * 16 + l15;
        if (n < 2048) {
            const float bias = bqk[n];
            const bool isQ = n < 1024;
            unsigned short* dst = isQ ? Qo : Ko;
            const int hd = isQ ? n : n - 1024;
            const float scale = isQ ? 0.125f : 1.0f;
            const int h = hd >> 6, d = hd & 63;
#pragma unroll
            for (int mi = 0; mi < 4; ++mi)
#pragma unroll
                for (int r = 0; r < 4; ++r) {
                    const int m = m0 + wm + mi * 16 + (quad << 2) + r;
                    const int b = m >> 11, s = m & 2047;
                    dst[((size_t)(b * 16 + h) * 2048 + s) * 64 + d] =
                        f2bf((acc[mi][ni][r] + bias) * scale);
                }
        } else {
            const float bias = bvv[n - 2048];
            const int hd = n - 2048;
            const int h = hd >> 6, d = hd & 63;
#pragma unroll
            for (int mi = 0; mi < 4; ++mi) {
                const int m = m0 + wm + mi * 16 + (quad << 2);
                const int b = m >> 11, s = m & 2047;
                u16x4 o4;
#pragma unroll
                for (int r = 0; r < 4; ++r) o4[r] = f2bf(acc[mi][ni][r] + bias);
                *(u16x4*)(VoT + ((size_t)(b * 16 + h) * 64 + d) * 2048 + s) = o4;
            }
        }
    }
}

// ---------------- kernel 4: causal flash attention, 32x32 MFMA ----------------
// grid 1024 = 32 q64-blocks (descending) x 32 bh (XCD-affine). Block 128 thr =
// 2 waves; wave w computes 32 q-rows (tile 2u+w) via S^T = K·Q^T. Both waves
// need exactly kv-tiles 0..u -> shared fragment-order staging via GLDS16.
__global__ __launch_bounds__(128, 4) void k_attn(
    const unsigned short* __restrict__ Q, const unsigned short* __restrict__ K,
    const unsigned short* __restrict__ Vt, float* __restrict__ out) {
    __shared__ __align__(16) unsigned short Ks[8 * 512];   // region (g*4+kb): 1KB each
    __shared__ __align__(16) unsigned short Vs[8 * 512];   // region (dt*4+m)
    const int tid = threadIdx.x;
    const int lane = tid & 63;
    const int w = tid >> 6;
    const int c = lane & 31;       // q column (C-layout col)
    const int hh = lane >> 5;      // half-wave
    const int gb = blockIdx.x;
    const int u = 31 - (gb >> 5);                    // q64 block, big first (LPT)
    const int bh = ((gb & 7) << 2) | ((gb >> 3) & 3);  // XCD-affine head mapping
    const size_t base = (size_t)bh * (2048 * 64);

    const int q_rel = w * 32 + c;
    const int q_abs = u * 64 + q_rel;

    // Q B-fragments: B[k=d][n=q], k = hh*8 + j
    bf16x8 qf[4];
    {
        const unsigned short* qp = Q + base + (size_t)q_abs * 64 + hh * 8;
#pragma unroll
        for (int kb = 0; kb < 4; ++kb) qf[kb] = *(const bf16x8*)(qp + kb * 16);
    }

    // wave w stages K kv-group g=w and V d-group dt=w, in fragment order:
    // lane L -> 16B at LDS base+16L == frag element for lane L.
    const unsigned short* kgp = K + base + (size_t)(w * 32 + c) * 64 + hh * 8;
    const unsigned short* vgp = Vt + base + (size_t)(w * 32 + c) * 2048 + hh * 8;
    unsigned short* kls = Ks + (w * 4) * 512;
    unsigned short* vls = Vs + (w * 4) * 512;

    floatx16 zero = {};
    floatx16 o2[2] = {};           // O^T: dt*32 d-rows, q cols
    float mrow = -3e38f, lrow = 0.f;

    for (int t = 0; t <= u; ++t) {
        __syncthreads();           // prior step's frag reads done
#pragma unroll
        for (int kb = 0; kb < 4; ++kb)
            GLDS16(kgp + t * 4096 + kb * 16, kls + kb * 512);
#pragma unroll
        for (int m = 0; m < 4; ++m)
            GLDS16(vgp + t * 64 + m * 16, vls + m * 512);
        __syncthreads();           // staged (vmcnt drain)

        // S^T = K·Q^T : C[kv][q]; lane: col q=c, rows kv = g*32+(i&3)+8*(i>>2)+4*hh
        floatx16 st[2]; st[0] = zero; st[1] = zero;
#pragma unroll
        for (int gg = 0; gg < 2; ++gg)
#pragma unroll
            for (int kb = 0; kb < 4; ++kb) {
                bf16x8 kf = *(const bf16x8*)&Ks[(gg * 4 + kb) * 512 + lane * 8];
                st[gg] = __builtin_amdgcn_mfma_f32_32x32x16_bf16(kf, qf[kb], st[gg], 0, 0, 0);
            }

        if (t == u) {              // diagonal: causal mask
#pragma unroll
            for (int gg = 0; gg < 2; ++gg)
#pragma unroll
                for (int i = 0; i < 16; ++i) {
                    int kv_rel = gg * 32 + (i & 3) + 8 * (i >> 2) + 4 * hh;
                    if (kv_rel > q_rel) st[gg][i] = -3e38f;
                }
        }

        // online softmax: per-lane scalar m,l (one q per lane)
        float mc = -3e38f;
#pragma unroll
        for (int gg = 0; gg < 2; ++gg)
#pragma unroll
            for (int i = 0; i < 16; ++i) mc = fmaxf(mc, st[gg][i]);
        mc = fmaxf(mc, __shfl_xor(mc, 32, 64));
        const float mnew = fmaxf(mrow, mc);
        const float alpha = __expf(mrow - mnew);
        mrow = mnew;
        float ls = 0.f;
#pragma unroll
        for (int gg = 0; gg < 2; ++gg)
#pragma unroll
            for (int i = 0; i < 16; ++i) {
                float p = __expf(st[gg][i] - mnew);
                st[gg][i] = p;
                ls += p;
            }
        ls += __shfl_xor(ls, 32, 64);
        lrow = lrow * alpha + ls;
#pragma unroll
        for (int dt = 0; dt < 2; ++dt) o2[dt] *= alpha;

        // P^T B-frags from St regs (pack + lane^32 half exchange), then O^T += V^T P^T
#pragma unroll
        for (int mb = 0; mb < 4; ++mb) {
            const int gg = mb >> 1, rb = (mb & 1) * 8;
            unsigned p0 = pk2(st[gg][rb + 0], st[gg][rb + 1]);   // kvm 4hh+0,1
            unsigned p1 = pk2(st[gg][rb + 2], st[gg][rb + 3]);   // kvm 4hh+2,3
            unsigned p2 = pk2(st[gg][rb + 4], st[gg][rb + 5]);   // kvm 8+4hh+0,1
            unsigned p3 = pk2(st[gg][rb + 6], st[gg][rb + 7]);   // kvm 8+4hh+2,3
            unsigned sA = hh ? p0 : p2;                          // send other half's need
            unsigned sB = hh ? p1 : p3;
            unsigned rA = (unsigned)__shfl_xor((int)sA, 32, 64);
            unsigned rB = (unsigned)__shfl_xor((int)sB, 32, 64);
            union { unsigned u4[4]; bf16x8 v; } pf;
            if (hh == 0) { pf.u4[0] = p0; pf.u4[1] = p1; pf.u4[2] = rA; pf.u4[3] = rB; }
            else         { pf.u4[0] = rA; pf.u4[1] = rB; pf.u4[2] = p2; pf.u4[3] = p3; }
#pragma unroll
            for (int dt = 0; dt < 2; ++dt) {
                bf16x8 vf = *(const bf16x8*)&Vs[(dt * 4 + mb) * 512 + lane * 8];
                o2[dt] = __builtin_amdgcn_mfma_f32_32x32x16_bf16(vf, pf.v, o2[dt], 0, 0, 0);
            }
        }
    }

    // epilogue: lane q=q_abs; d = dt*32 + 8*rr + 4*hh + (0..3) -> float4 stores
    const int b = bh >> 4, head = bh & 15;
    const float inv = 1.0f / lrow;
    float* op = out + (size_t)(b * 2048 + q_abs) * 1024 + head * 64;
#pragma unroll
    for (int dt = 0; dt < 2; ++dt)
#pragma unroll
        for (int rr = 0; rr < 4; ++rr) {
            float4 v4 = make_float4(o2[dt][rr * 4 + 0] * inv, o2[dt][rr * 4 + 1] * inv,
                                    o2[dt][rr * 4 + 2] * inv, o2[dt][rr * 4 + 3] * inv);
            *(float4*)(op + dt * 32 + rr * 8 + hh * 4) = v4;
        }
}

extern "C" void kernel_launch(void* const* d_in, const int* in_sizes, int n_in,
                              void* d_out, int out_size, void* d_ws, size_t ws_size,
                              hipStream_t stream) {
    const float* hidden = (const float*)d_in[0];
    const float* Wqk    = (const float*)d_in[1];
    const float* bqk    = (const float*)d_in[2];
    const float* Wv     = (const float*)d_in[3];
    const float* bvv    = (const float*)d_in[4];
    float* out = (float*)d_out;

    unsigned short* Abf = (unsigned short*)d_ws;
    unsigned short* Wt  = Abf + 4096 * 1024;
    unsigned short* Qo  = Wt + 3072 * 1024;
    unsigned short* Ko  = Qo + 32 * 2048 * 64;
    unsigned short* VoT = Ko + 32 * 2048 * 64;

    k_convert<<<2048, 256, 0, stream>>>(hidden, Abf);
    k_transpose<<<dim3(48, 16), 256, 0, stream>>>(Wqk, Wv, Wt);
    k_gemm_qkv<<<dim3(32, 24), 256, 0, stream>>>(Abf, Wt, bqk, bvv, Qo, Ko, VoT);
    k_attn<<<1024, 128, 0, stream>>>(Qo, Ko, VoT, out);
}